// Round 14
// baseline (251.314 us; speedup 1.0000x reference)
//
#include <hip/hip_runtime.h>
#include <math.h>

#define G_    64
#define NPG_  1600
#define N_    (G_*NPG_)     // 102400
#define EPG_  51200
#define E_    (G_*EPG_)     // 3276800
#define FIN_  512
#define HOUT_ 512
#define KEEP_ 1280

typedef _Float16 f16x8 __attribute__((ext_vector_type(8)));
typedef float f32x4 __attribute__((ext_vector_type(4)));
#define WSTR_ 520   // halfs per n-row (512 + 8 pad)

// ---------------------------------------------------------------------------
// K1+K2 fused heterogeneous kernel: blocks 0-63 run the CSR build (consumes
// esrc/edst only); blocks 64-463 run the MFMA xW1 GEMM (consumes x/W1 only).
// Independent once the dis multiply is deferred to conv1l staging.
// Verified r13: -28us vs serial launches.
// ---------------------------------------------------------------------------
union BXShared {
  struct {
    unsigned short csrs[EPG_];      // 102,400 B
    int hist[NPG_];                 // 6,400 B
    int wsum[16];
  } b;
  struct {
    _Float16 wls[2][16][WSTR_];     // 33,280 B
  } x;
};

__global__ __launch_bounds__(1024, 4) void k_bx(
    const int* __restrict__ esrc, const int* __restrict__ edst,
    int* __restrict__ offs, int* __restrict__ rend,
    float* __restrict__ dis, unsigned short* __restrict__ csr,
    const float* __restrict__ x, const float* __restrict__ W1,
    float* __restrict__ hd) {
  __shared__ BXShared sm;
  const int t = threadIdx.x;
  const int lane = t & 63, wid = t >> 6;

  if (blockIdx.x < 64) {
    // ---------------- build path ----------
    const int g = blockIdx.x;
    const int eb = g * EPG_, nb = g * NPG_;

    for (int i = t; i < NPG_; i += 1024) sm.b.hist[i] = 0;
    __syncthreads();
    for (int e = t; e < EPG_; e += 1024)
      atomicAdd(&sm.b.hist[edst[eb + e] - nb], 1);
    __syncthreads();

    int c0 = 0, c1 = 0;
    if (t < 800) { c0 = sm.b.hist[2 * t]; c1 = sm.b.hist[2 * t + 1]; }
    const int val = c0 + c1;
    int incl = val;
#pragma unroll
    for (int m = 1; m < 64; m <<= 1) {
      const int u = __shfl_up(incl, m);
      if (lane >= m) incl += u;
    }
    if (lane == 63) sm.b.wsum[wid] = incl;
    __syncthreads();
    int woff = 0;
    for (int w2 = 0; w2 < wid; ++w2) woff += sm.b.wsum[w2];
    incl += woff;
    if (t < 800) {
      const int excl = incl - val;          // LOCAL edge offset
      const int p0 = excl, p1 = p0 + c0;
      offs[nb + 2 * t] = eb + p0;     rend[nb + 2 * t] = eb + p1;
      offs[nb + 2 * t + 1] = eb + p1; rend[nb + 2 * t + 1] = eb + p1 + c1;
      dis[nb + 2 * t] = rsqrtf((float)c0 + 1.0f);
      dis[nb + 2 * t + 1] = rsqrtf((float)c1 + 1.0f);
      sm.b.hist[2 * t] = p0;          // reuse as LOCAL cursor
      sm.b.hist[2 * t + 1] = p1;
    }
    __syncthreads();
    for (int e = t; e < EPG_; e += 1024) {
      const int s = esrc[eb + e];
      const int d = edst[eb + e] - nb;
      const int p = atomicAdd(&sm.b.hist[d], 1);
      sm.b.csrs[p] = (unsigned short)(s - nb);
    }
    __syncthreads();
    const uint4* s4 = reinterpret_cast<const uint4*>(sm.b.csrs);
    uint4* d4 = reinterpret_cast<uint4*>(csr + eb);
    for (int i = t; i < EPG_ / 8; i += 1024) d4[i] = s4[i];
  } else {
    // ---------------- xw1 path (MFMA fp16 2-split, NO dis multiply) -------
    for (int i = t; i < FIN_ * 16; i += 1024) {
      const int k = i >> 4, n = i & 15;
      const float w = W1[i];
      const _Float16 w1 = (_Float16)w;
      const float r = w - (float)w1;              // exact (Sterbenz)
      sm.x.wls[0][n][k] = w1;
      sm.x.wls[1][n][k] = (_Float16)r;
    }
    __syncthreads();

    const int g = lane >> 4, m = lane & 15;       // m: A-row / B-col / D-col
    const int tile = (blockIdx.x - 64) * 16 + wid; // 400 blocks x 16 waves
    const int rb = tile * 16;

    const float* xrow = x + (size_t)(rb + m) * FIN_ + g * 8;
    const _Float16* wb1 = &sm.x.wls[0][m][g * 8];
    const _Float16* wb2 = &sm.x.wls[1][m][g * 8];

    f32x4 acc = {0.f, 0.f, 0.f, 0.f};
#pragma unroll
    for (int t4 = 0; t4 < 16; ++t4) {
      const float4 p0 = *reinterpret_cast<const float4*>(xrow + t4 * 32);
      const float4 p1 = *reinterpret_cast<const float4*>(xrow + t4 * 32 + 4);
      const float xv[8] = {p0.x, p0.y, p0.z, p0.w, p1.x, p1.y, p1.z, p1.w};
      f16x8 a1, a2;
#pragma unroll
      for (int j = 0; j < 8; ++j) {
        const _Float16 h = (_Float16)xv[j];
        a1[j] = h;
        a2[j] = (_Float16)(xv[j] - (float)h);     // residual split (exact sub)
      }
      const f16x8 b1 = *reinterpret_cast<const f16x8*>(wb1 + t4 * 32);
      const f16x8 b2 = *reinterpret_cast<const f16x8*>(wb2 + t4 * 32);
      acc = __builtin_amdgcn_mfma_f32_16x16x32_f16(a1, b1, acc, 0, 0, 0);
      acc = __builtin_amdgcn_mfma_f32_16x16x32_f16(a1, b2, acc, 0, 0, 0);
      acc = __builtin_amdgcn_mfma_f32_16x16x32_f16(a2, b1, acc, 0, 0, 0);
    }

    // D: col = m, row = rb + g*4 + reg (raw xW1, dis applied in conv1l)
#pragma unroll
    for (int rg = 0; rg < 4; ++rg)
      hd[(size_t)(rb + g * 4 + rg) * 16 + m] = acc[rg];
  }
}

// ---------------------------------------------------------------------------
// K3: conv1 gather, LDS-staged.  Stage-time multiply hds = hd_raw * dis.
// ---------------------------------------------------------------------------
__global__ __launch_bounds__(1024) void k_conv1l(
    const unsigned short* __restrict__ csr, const int* __restrict__ offs,
    const int* __restrict__ rend, const float* __restrict__ hd,
    const float* __restrict__ dis, const float* __restrict__ b1,
    const float* __restrict__ Wrel, const float* __restrict__ Wroot,
    float* __restrict__ h1, float* __restrict__ rarr, float* __restrict__ tarr) {
  __shared__ float hds[NPG_ * 16];                // 102,400 B
  const int g = blockIdx.x >> 2, q = blockIdx.x & 3;
  const int nb = g * NPG_;
  const int t = threadIdx.x;
  {
    const float4* src = reinterpret_cast<const float4*>(hd + (size_t)nb * 16);
    float4* dst = reinterpret_cast<float4*>(hds);
    for (int i = t; i < NPG_ * 4; i += 1024) {
      const float4 v = src[i];
      const float dd = dis[nb + (i >> 2)];
      dst[i] = make_float4(v.x * dd, v.y * dd, v.z * dd, v.w * dd);
    }
  }
  __syncthreads();
  const int c = t & 15;
  const float bb = b1[c], wr = Wrel[c], wo = Wroot[c];
  const int vend = q * 400 + 400;
  for (int vl = q * 400 + (t >> 4); vl < vend; vl += 64) {
    const int v = nb + vl;
    const int rs = offs[v], re = rend[v];
    float acc = 0.f;
    int k = rs;
    for (; k + 4 <= re; k += 4) {
      const int s0 = csr[k], s1 = csr[k + 1];
      const int s2 = csr[k + 2], s3 = csr[k + 3];
      acc += hds[s0 * 16 + c] + hds[s1 * 16 + c];
      acc += hds[s2 * 16 + c] + hds[s3 * 16 + c];
    }
    for (; k < re; ++k) acc += hds[csr[k] * 16 + c];
    const float dd = dis[v];
    float val = fmaf(acc + hds[vl * 16 + c], dd, bb);
    val = fmaxf(val, 0.f);
    h1[(size_t)v * 16 + c] = val;
    float r = val * wr;
    float tt = val * wo;
#pragma unroll
    for (int m = 1; m < 16; m <<= 1) {
      r += __shfl_xor(r, m);
      tt += __shfl_xor(tt, m);
    }
    if (c == 0) { rarr[v] = r; tarr[v] = tt; }
  }
}

// ---------------------------------------------------------------------------
// K4a: score gather at full occupancy.  5 blocks/graph x 320 thr.
// ---------------------------------------------------------------------------
__global__ __launch_bounds__(320) void k_score(
    const unsigned short* __restrict__ csr, const int* __restrict__ offs,
    const int* __restrict__ rend, const float* __restrict__ rarr,
    const float* __restrict__ tarr, const float* __restrict__ brel,
    float* __restrict__ scoreg, unsigned* __restrict__ uug) {
  __shared__ float rar[NPG_];
  const int g = blockIdx.x / 5, q = blockIdx.x % 5;   // grid 320
  const int nb = g * NPG_;
  const int t = threadIdx.x;
  for (int i = t; i < NPG_; i += 320) rar[i] = rarr[nb + i];
  __syncthreads();
  const int vl = q * 320 + t;
  const int v = nb + vl;
  const int rs = offs[v], re = rend[v];
  float sum = 0.f;
  int k = rs;
  for (; k + 4 <= re; k += 4) {
    sum += rar[csr[k]] + rar[csr[k + 1]];
    sum += rar[csr[k + 2]] + rar[csr[k + 3]];
  }
  for (; k < re; ++k) sum += rar[csr[k]];
  const float s = tanhf(sum + brel[0] + tarr[v]);
  scoreg[v] = s;
  const unsigned ub = __float_as_uint(s);
  uug[v] = (ub & 0x80000000u) ? ~ub : (ub | 0x80000000u);
}

// ---------------------------------------------------------------------------
// K4b: per-graph radix-select top-K (stable, index tie-break) on staged keys.
// Also zeroes the out slice (consumed by the MFMA gemm2pool's atomics).
// ---------------------------------------------------------------------------
__global__ __launch_bounds__(1024) void k_topk(
    const unsigned* __restrict__ uug, int* __restrict__ kept,
    float* __restrict__ out) {
  __shared__ unsigned uu[NPG_];
  __shared__ int kp[NPG_];
  __shared__ int hist[256];
  __shared__ int part[16];
  __shared__ int scal[2];
  const int g = blockIdx.x, t = threadIdx.x;
  const int lane = t & 63, wid = t >> 6;
  const int nb = g * NPG_;

  for (int i = t; i < NPG_; i += 1024) uu[i] = uug[nb + i];
  if (t == 0) { scal[0] = 0; scal[1] = KEEP_; }
  __syncthreads();

  const unsigned maskTab[4] = {0u, 0xFF000000u, 0xFFFF0000u, 0xFFFFFF00u};
  const int shTab[4] = {24, 16, 8, 0};
  for (int pass = 0; pass < 4; ++pass) {
    const unsigned lo = (unsigned)scal[0];
    const int remc = scal[1];
    const unsigned msk = maskTab[pass];
    const int sh = shTab[pass];
    if (t < 256) hist[t] = 0;
    __syncthreads();
    for (int v = t; v < NPG_; v += 1024) {
      const unsigned u = uu[v];
      if (((u ^ lo) & msk) == 0) atomicAdd(&hist[(u >> sh) & 255], 1);
    }
    __syncthreads();
    int hv = 0;
    if (t < 256) hv = hist[t];
    int incl = hv;
#pragma unroll
    for (int m = 1; m < 64; m <<= 1) {
      const int u2 = __shfl_up(incl, m);
      if (lane >= m) incl += u2;
    }
    if (t < 256 && lane == 63) part[wid] = incl;
    __syncthreads();
    if (t < 256) {
      int woff = 0;
      for (int w2 = 0; w2 < wid; ++w2) woff += part[w2];
      const int tot = part[0] + part[1] + part[2] + part[3];
      const int sb = tot - (incl + woff) + hv;    // suffix sum from bin t
      const int sb1 = sb - hv;
      if (sb >= remc && sb1 < remc) {             // unique boundary bin
        scal[0] = (int)(lo | ((unsigned)t << sh));
        scal[1] = remc - sb1;
      }
    }
    __syncthreads();
  }
  const unsigned T = (unsigned)scal[0];
  const int remT = scal[1];

  const int i0 = 2 * t, i1 = 2 * t + 1;
  int f0 = 0, f1 = 0;
  if (i0 < NPG_) f0 = (uu[i0] == T);
  if (i1 < NPG_) f1 = (uu[i1] == T);
  int incl2 = f0 + f1;
#pragma unroll
  for (int m = 1; m < 64; m <<= 1) {
    const int u2 = __shfl_up(incl2, m);
    if (lane >= m) incl2 += u2;
  }
  if (lane == 63) part[wid] = incl2;
  __syncthreads();
  int woff2 = 0;
  for (int w2 = 0; w2 < wid; ++w2) woff2 += part[w2];
  const int excl = incl2 + woff2 - (f0 + f1);
  if (i0 < NPG_) kp[i0] = (uu[i0] > T) || (f0 && excl < remT);
  if (i1 < NPG_) kp[i1] = (uu[i1] > T) || (f1 && (excl + f0) < remT);
  __syncthreads();
  for (int v = t; v < NPG_; v += 1024) kept[nb + v] = kp[v];
  if (t < HOUT_) out[g * HOUT_ + t] = 0.f;
}

// ---------------------------------------------------------------------------
// K4c: filtered degree + dis2 + wv + h1w at full occupancy.
// ---------------------------------------------------------------------------
__global__ __launch_bounds__(320) void k_post(
    const unsigned short* __restrict__ csr, const int* __restrict__ offs,
    const int* __restrict__ rend, const int* __restrict__ kept,
    const float* __restrict__ scoreg, const float* __restrict__ h1,
    float* __restrict__ dis2, float* __restrict__ h1w) {
  __shared__ int kp[NPG_];
  __shared__ float wvs[320];
  const int g = blockIdx.x / 5, q = blockIdx.x % 5;   // grid 320
  const int nb = g * NPG_;
  const int t = threadIdx.x;
  for (int i = t; i < NPG_; i += 320) kp[i] = kept[nb + i];
  __syncthreads();
  const int vl = q * 320 + t;
  const int v = nb + vl;
  float w = 0.f;
  if (kp[vl]) {
    const int rs = offs[v], re = rend[v];
    int c2 = 0, k = rs;
    for (; k + 4 <= re; k += 4) {
      c2 += kp[csr[k]] + kp[csr[k + 1]];
      c2 += kp[csr[k + 2]] + kp[csr[k + 3]];
    }
    for (; k < re; ++k) c2 += kp[csr[k]];
    const float d2 = rsqrtf((float)c2 + 1.0f);
    dis2[v] = d2;
    w = scoreg[v] * d2;
  }
  wvs[t] = w;
  __syncthreads();
  const size_t base = (size_t)(nb + q * 320) * 16;
  for (int i = t; i < 320 * 16; i += 320)
    h1w[base + i] = h1[base + i] * wvs[i >> 4];
}

// ---------------------------------------------------------------------------
// K5: conv2 gather, LDS-staged.
// ---------------------------------------------------------------------------
__global__ __launch_bounds__(1024) void k_conv2l(
    const unsigned short* __restrict__ csr, const int* __restrict__ offs,
    const int* __restrict__ rend, const float* __restrict__ h1w,
    const int* __restrict__ kept, const float* __restrict__ dis2,
    float* __restrict__ y16) {
  __shared__ float hds[NPG_ * 16];                // 102,400 B
  const int g = blockIdx.x >> 2, q = blockIdx.x & 3;
  const int nb = g * NPG_;
  const int t = threadIdx.x;
  {
    const float4* src = reinterpret_cast<const float4*>(h1w + (size_t)nb * 16);
    float4* dst = reinterpret_cast<float4*>(hds);
    for (int i = t; i < NPG_ * 4; i += 1024) dst[i] = src[i];
  }
  __syncthreads();
  const int c = t & 15;
  const int vend = q * 400 + 400;
  for (int vl = q * 400 + (t >> 4); vl < vend; vl += 64) {
    const int v = nb + vl;
    if (!kept[v]) continue;                       // uniform per 16-group
    const int rs = offs[v], re = rend[v];
    float acc = 0.f;
    int k = rs;
    for (; k + 4 <= re; k += 4) {
      const int s0 = csr[k], s1 = csr[k + 1];
      const int s2 = csr[k + 2], s3 = csr[k + 3];
      acc += hds[s0 * 16 + c] + hds[s1 * 16 + c];
      acc += hds[s2 * 16 + c] + hds[s3 * 16 + c];
    }
    for (; k < re; ++k) acc += hds[csr[k] * 16 + c];
    acc += hds[vl * 16 + c];                      // self loop
    y16[(size_t)v * 16 + c] = acc * dis2[v];
  }
}

// ---------------------------------------------------------------------------
// K6: out[g] += relu(y16@W2 + b2)/K via MFMA 16x16x32_f16 fp16 2-split.
// Old scalar version: 1.68 GFLOP = 13.1M wave-inst ~ 11us pure VALU + loads.
// MFMA packs the K=32 slots as the split: MFMA1 = [y1|y2]*[w1;w1] =
// y1w1 + y2w1; MFMA2 = [y1|y1]*[w2;0] = y1w2 (the xw1-proven 3-product
// scheme).  W2 split+transposed to LDS wt[2][512 j][16 k] -> B-frag =
// 1 ds_read_b128.  A built per 16-node tile (2 masked float4 loads + cvt;
// A zeroed for dropped rows blocks NaN; km mask after relu kills relu(b2)).
// relu+mask per D then accumulate -> acc[32 jt][4]; reduce shfl(16,32) ->
// LDS -> global atomics.  256 blocks (4/graph) x 512 thr.
// ---------------------------------------------------------------------------
__global__ __launch_bounds__(512, 1) void k_gemm2pool(
    const float* __restrict__ y16, const int* __restrict__ kept,
    const float* __restrict__ W2, const float* __restrict__ b2,
    float* __restrict__ out) {
  __shared__ _Float16 wt[2][HOUT_][16];           // 32,768 B  [split][j][k]
  __shared__ float b2s[HOUT_];
  __shared__ float red[HOUT_];
  const int tid = threadIdx.x;

  for (int i = tid; i < 16 * HOUT_; i += 512) {   // i = k*512 + j: coalesced
    const int j = i & 511;
    const int k = i >> 9;
    const float w = W2[i];
    const _Float16 w1 = (_Float16)w;
    wt[0][j][k] = w1;
    wt[1][j][k] = (_Float16)(w - (float)w1);      // exact (Sterbenz)
  }
  for (int i = tid; i < HOUT_; i += 512) { b2s[i] = b2[i]; red[i] = 0.f; }
  __syncthreads();

  const int g = blockIdx.x >> 2, q = blockIdx.x & 3;   // grid 256
  const int nb = g * NPG_ + q * 400;                   // 400 nodes = 25 tiles
  const int lane = tid & 63, wid = tid >> 6;           // 8 waves
  const int gg = lane >> 4, m = lane & 15;

  float accv[32][4];
#pragma unroll
  for (int jt = 0; jt < 32; ++jt)
#pragma unroll
    for (int r = 0; r < 4; ++r) accv[jt][r] = 0.f;

  for (int tt = wid; tt < 25; tt += 8) {
    const int base = nb + tt * 16;
    // A: lane (gg,m) reads y16[base+m][k0..k0+7], k0=(gg&1)*8 (A k=gg*8+idx)
    const int k0 = (gg & 1) * 8;
    const float* yr = y16 + (size_t)(base + m) * 16 + k0;
    float4 pa = make_float4(0.f, 0.f, 0.f, 0.f);
    float4 pb = make_float4(0.f, 0.f, 0.f, 0.f);
    if (kept[base + m]) {                         // zero A row if dropped
      pa = *reinterpret_cast<const float4*>(yr);
      pb = *reinterpret_cast<const float4*>(yr + 4);
    }
    const float yv[8] = {pa.x, pa.y, pa.z, pa.w, pb.x, pb.y, pb.z, pb.w};
    f16x8 y1, y2;
#pragma unroll
    for (int jj = 0; jj < 8; ++jj) {
      const _Float16 h = (_Float16)yv[jj];
      y1[jj] = h;
      y2[jj] = (_Float16)(yv[jj] - (float)h);     // residual split (exact)
    }
    const f16x8 A1 = (gg < 2) ? y1 : y2;          // [y1 | y2]
    const f16x8 A2 = y1;                          // [y1 | y1]
    float km[4];                                  // D-row kept mask
#pragma unroll
    for (int r = 0; r < 4; ++r)
      km[r] = kept[base + gg * 4 + r] ? 1.f : 0.f;

#pragma unroll 4
    for (int jt = 0; jt < 32; ++jt) {
      const int j = jt * 16 + m;
      // B1 = [w1; w1]: k<16 -> wt0[j][k], k>=16 -> wt0[j][k-16]
      const f16x8 B1 = *reinterpret_cast<const f16x8*>(&wt[0][j][(gg & 1) * 8]);
      // B2 = [w2; 0]
      f16x8 B2 = {0, 0, 0, 0, 0, 0, 0, 0};
      if (gg < 2) B2 = *reinterpret_cast<const f16x8*>(&wt[1][j][gg * 8]);
      f32x4 d = {0.f, 0.f, 0.f, 0.f};
      d = __builtin_amdgcn_mfma_f32_16x16x32_f16(A1, B1, d, 0, 0, 0);
      d = __builtin_amdgcn_mfma_f32_16x16x32_f16(A2, B2, d, 0, 0, 0);
      const float bj = b2s[j];
#pragma unroll
      for (int r = 0; r < 4; ++r)
        accv[jt][r] += km[r] * fmaxf(d[r] + bj, 0.f);
    }
  }

  // reduce: sum 4 row-regs, fold gg-groups (lane bits 4,5), LDS across waves
#pragma unroll
  for (int jt = 0; jt < 32; ++jt) {
    float s = accv[jt][0] + accv[jt][1] + accv[jt][2] + accv[jt][3];
    s += __shfl_xor(s, 16);
    s += __shfl_xor(s, 32);
    accv[jt][0] = s;
  }
  if (lane < 16) {
#pragma unroll
    for (int jt = 0; jt < 32; ++jt)
      atomicAdd(&red[jt * 16 + lane], accv[jt][0]);
  }
  __syncthreads();
  for (int i = tid; i < HOUT_; i += 512)
    atomicAdd(&out[g * HOUT_ + i], red[i] * (1.0f / (float)KEEP_));
}

// ---------------------------------------------------------------------------
extern "C" void kernel_launch(void* const* d_in, const int* in_sizes, int n_in,
                              void* d_out, int out_size, void* d_ws, size_t ws_size,
                              hipStream_t stream) {
  (void)in_sizes; (void)n_in; (void)out_size; (void)ws_size;
  const float* x     = (const float*)d_in[0];
  const int*   ei    = (const int*)  d_in[1];
  const float* W1    = (const float*)d_in[3];
  const float* b1    = (const float*)d_in[4];
  const float* Wrel  = (const float*)d_in[5];
  const float* brel  = (const float*)d_in[6];
  const float* Wroot = (const float*)d_in[7];
  const float* W2    = (const float*)d_in[8];
  const float* b2    = (const float*)d_in[9];
  const int* esrc = ei;
  const int* edst = ei + E_;

  // slab quarters: hd / h1 / h1w / y16.  hd (q0) is dead after k_conv1l ->
  // reused for radix keys (uug) and scores (scoreg).
  char* ws = (char*)d_ws;
  float*          hd     = (float*)(ws);                    // q0: 6,553,600 B
  unsigned*       uug    = (unsigned*)(ws);                 //   reuse of q0
  float*          scoreg = (float*)(ws + 409600);           //   reuse of q0
  float*          h1     = (float*)(ws + 6553600);          // q1
  float*          h1w    = (float*)(ws + 13107200);         // q2
  float*          y16    = (float*)(ws + 19660800);         // q3
  unsigned short* csr    = (unsigned short*)(ws + 26214400);// 6,553,600 B
  int*            offs   = (int*)(ws + 32768000);
  int*            rendp  = (int*)(ws + 33177600);
  float*          dis    = (float*)(ws + 33587200);
  int*            kept   = (int*)(ws + 33996800);
  float*          rarr   = (float*)(ws + 34406400);
  float*          tarr   = (float*)(ws + 34816000);
  float*          dis2   = (float*)(ws + 35225600);
  float*          out    = (float*)d_out;

  hipLaunchKernelGGL(k_bx,        dim3(464),   dim3(1024), 0, stream,
                     esrc, edst, offs, rendp, dis, csr, x, W1, hd);
  hipLaunchKernelGGL(k_conv1l,    dim3(256),   dim3(1024), 0, stream,
                     csr, offs, rendp, hd, dis, b1, Wrel, Wroot, h1, rarr, tarr);
  hipLaunchKernelGGL(k_score,     dim3(320),   dim3(320),  0, stream,
                     csr, offs, rendp, rarr, tarr, brel, scoreg, uug);
  hipLaunchKernelGGL(k_topk,      dim3(G_),    dim3(1024), 0, stream,
                     uug, kept, out);
  hipLaunchKernelGGL(k_post,      dim3(320),   dim3(320),  0, stream,
                     csr, offs, rendp, kept, scoreg, h1, dis2, h1w);
  hipLaunchKernelGGL(k_conv2l,    dim3(256),   dim3(1024), 0, stream,
                     csr, offs, rendp, h1w, kept, dis2, y16);
  hipLaunchKernelGGL(k_gemm2pool, dim3(256),   dim3(512),  0, stream,
                     y16, kept, W2, b2, out);
}

// Round 15
// 186.011 us; speedup vs baseline: 1.3511x; 1.3511x over previous
//
#include <hip/hip_runtime.h>
#include <math.h>

#define G_    64
#define NPG_  1600
#define N_    (G_*NPG_)     // 102400
#define EPG_  51200
#define E_    (G_*EPG_)     // 3276800
#define FIN_  512
#define HOUT_ 512
#define KEEP_ 1280

typedef _Float16 f16x8 __attribute__((ext_vector_type(8)));
typedef float f32x4 __attribute__((ext_vector_type(4)));
#define WSTR_ 520   // halfs per n-row (512 + 8 pad)

// ---------------------------------------------------------------------------
// K1+K2 fused heterogeneous kernel: blocks 0-63 run the CSR build (consumes
// esrc/edst only); blocks 64-463 run the MFMA xW1 GEMM (consumes x/W1 only).
// Independent once the dis multiply is deferred to conv1l staging.
// Verified r13: -28us vs serial launches.
// ---------------------------------------------------------------------------
union BXShared {
  struct {
    unsigned short csrs[EPG_];      // 102,400 B
    int hist[NPG_];                 // 6,400 B
    int wsum[16];
  } b;
  struct {
    _Float16 wls[2][16][WSTR_];     // 33,280 B
  } x;
};

__global__ __launch_bounds__(1024, 4) void k_bx(
    const int* __restrict__ esrc, const int* __restrict__ edst,
    int* __restrict__ offs, int* __restrict__ rend,
    float* __restrict__ dis, unsigned short* __restrict__ csr,
    const float* __restrict__ x, const float* __restrict__ W1,
    float* __restrict__ hd) {
  __shared__ BXShared sm;
  const int t = threadIdx.x;
  const int lane = t & 63, wid = t >> 6;

  if (blockIdx.x < 64) {
    // ---------------- build path ----------
    const int g = blockIdx.x;
    const int eb = g * EPG_, nb = g * NPG_;

    for (int i = t; i < NPG_; i += 1024) sm.b.hist[i] = 0;
    __syncthreads();
    for (int e = t; e < EPG_; e += 1024)
      atomicAdd(&sm.b.hist[edst[eb + e] - nb], 1);
    __syncthreads();

    int c0 = 0, c1 = 0;
    if (t < 800) { c0 = sm.b.hist[2 * t]; c1 = sm.b.hist[2 * t + 1]; }
    const int val = c0 + c1;
    int incl = val;
#pragma unroll
    for (int m = 1; m < 64; m <<= 1) {
      const int u = __shfl_up(incl, m);
      if (lane >= m) incl += u;
    }
    if (lane == 63) sm.b.wsum[wid] = incl;
    __syncthreads();
    int woff = 0;
    for (int w2 = 0; w2 < wid; ++w2) woff += sm.b.wsum[w2];
    incl += woff;
    if (t < 800) {
      const int excl = incl - val;          // LOCAL edge offset
      const int p0 = excl, p1 = p0 + c0;
      offs[nb + 2 * t] = eb + p0;     rend[nb + 2 * t] = eb + p1;
      offs[nb + 2 * t + 1] = eb + p1; rend[nb + 2 * t + 1] = eb + p1 + c1;
      dis[nb + 2 * t] = rsqrtf((float)c0 + 1.0f);
      dis[nb + 2 * t + 1] = rsqrtf((float)c1 + 1.0f);
      sm.b.hist[2 * t] = p0;          // reuse as LOCAL cursor
      sm.b.hist[2 * t + 1] = p1;
    }
    __syncthreads();
    for (int e = t; e < EPG_; e += 1024) {
      const int s = esrc[eb + e];
      const int d = edst[eb + e] - nb;
      const int p = atomicAdd(&sm.b.hist[d], 1);
      sm.b.csrs[p] = (unsigned short)(s - nb);
    }
    __syncthreads();
    const uint4* s4 = reinterpret_cast<const uint4*>(sm.b.csrs);
    uint4* d4 = reinterpret_cast<uint4*>(csr + eb);
    for (int i = t; i < EPG_ / 8; i += 1024) d4[i] = s4[i];
  } else {
    // ---------------- xw1 path (MFMA fp16 2-split, NO dis multiply) -------
    for (int i = t; i < FIN_ * 16; i += 1024) {
      const int k = i >> 4, n = i & 15;
      const float w = W1[i];
      const _Float16 w1 = (_Float16)w;
      const float r = w - (float)w1;              // exact (Sterbenz)
      sm.x.wls[0][n][k] = w1;
      sm.x.wls[1][n][k] = (_Float16)r;
    }
    __syncthreads();

    const int g = lane >> 4, m = lane & 15;       // m: A-row / B-col / D-col
    const int tile = (blockIdx.x - 64) * 16 + wid; // 400 blocks x 16 waves
    const int rb = tile * 16;

    const float* xrow = x + (size_t)(rb + m) * FIN_ + g * 8;
    const _Float16* wb1 = &sm.x.wls[0][m][g * 8];
    const _Float16* wb2 = &sm.x.wls[1][m][g * 8];

    f32x4 acc = {0.f, 0.f, 0.f, 0.f};
#pragma unroll
    for (int t4 = 0; t4 < 16; ++t4) {
      const float4 p0 = *reinterpret_cast<const float4*>(xrow + t4 * 32);
      const float4 p1 = *reinterpret_cast<const float4*>(xrow + t4 * 32 + 4);
      const float xv[8] = {p0.x, p0.y, p0.z, p0.w, p1.x, p1.y, p1.z, p1.w};
      f16x8 a1, a2;
#pragma unroll
      for (int j = 0; j < 8; ++j) {
        const _Float16 h = (_Float16)xv[j];
        a1[j] = h;
        a2[j] = (_Float16)(xv[j] - (float)h);     // residual split (exact sub)
      }
      const f16x8 b1 = *reinterpret_cast<const f16x8*>(wb1 + t4 * 32);
      const f16x8 b2 = *reinterpret_cast<const f16x8*>(wb2 + t4 * 32);
      acc = __builtin_amdgcn_mfma_f32_16x16x32_f16(a1, b1, acc, 0, 0, 0);
      acc = __builtin_amdgcn_mfma_f32_16x16x32_f16(a1, b2, acc, 0, 0, 0);
      acc = __builtin_amdgcn_mfma_f32_16x16x32_f16(a2, b1, acc, 0, 0, 0);
    }

    // D: col = m, row = rb + g*4 + reg (raw xW1, dis applied in conv1l)
#pragma unroll
    for (int rg = 0; rg < 4; ++rg)
      hd[(size_t)(rb + g * 4 + rg) * 16 + m] = acc[rg];
  }
}

// ---------------------------------------------------------------------------
// K3: conv1 gather, LDS-staged.  Stage-time multiply hds = hd_raw * dis.
// ---------------------------------------------------------------------------
__global__ __launch_bounds__(1024) void k_conv1l(
    const unsigned short* __restrict__ csr, const int* __restrict__ offs,
    const int* __restrict__ rend, const float* __restrict__ hd,
    const float* __restrict__ dis, const float* __restrict__ b1,
    const float* __restrict__ Wrel, const float* __restrict__ Wroot,
    float* __restrict__ h1, float* __restrict__ rarr, float* __restrict__ tarr) {
  __shared__ float hds[NPG_ * 16];                // 102,400 B
  const int g = blockIdx.x >> 2, q = blockIdx.x & 3;
  const int nb = g * NPG_;
  const int t = threadIdx.x;
  {
    const float4* src = reinterpret_cast<const float4*>(hd + (size_t)nb * 16);
    float4* dst = reinterpret_cast<float4*>(hds);
    for (int i = t; i < NPG_ * 4; i += 1024) {
      const float4 v = src[i];
      const float dd = dis[nb + (i >> 2)];
      dst[i] = make_float4(v.x * dd, v.y * dd, v.z * dd, v.w * dd);
    }
  }
  __syncthreads();
  const int c = t & 15;
  const float bb = b1[c], wr = Wrel[c], wo = Wroot[c];
  const int vend = q * 400 + 400;
  for (int vl = q * 400 + (t >> 4); vl < vend; vl += 64) {
    const int v = nb + vl;
    const int rs = offs[v], re = rend[v];
    float acc = 0.f;
    int k = rs;
    for (; k + 4 <= re; k += 4) {
      const int s0 = csr[k], s1 = csr[k + 1];
      const int s2 = csr[k + 2], s3 = csr[k + 3];
      acc += hds[s0 * 16 + c] + hds[s1 * 16 + c];
      acc += hds[s2 * 16 + c] + hds[s3 * 16 + c];
    }
    for (; k < re; ++k) acc += hds[csr[k] * 16 + c];
    const float dd = dis[v];
    float val = fmaf(acc + hds[vl * 16 + c], dd, bb);
    val = fmaxf(val, 0.f);
    h1[(size_t)v * 16 + c] = val;
    float r = val * wr;
    float tt = val * wo;
#pragma unroll
    for (int m = 1; m < 16; m <<= 1) {
      r += __shfl_xor(r, m);
      tt += __shfl_xor(tt, m);
    }
    if (c == 0) { rarr[v] = r; tarr[v] = tt; }
  }
}

// ---------------------------------------------------------------------------
// K4a: score gather at full occupancy.  5 blocks/graph x 320 thr.
// ---------------------------------------------------------------------------
__global__ __launch_bounds__(320) void k_score(
    const unsigned short* __restrict__ csr, const int* __restrict__ offs,
    const int* __restrict__ rend, const float* __restrict__ rarr,
    const float* __restrict__ tarr, const float* __restrict__ brel,
    float* __restrict__ scoreg, unsigned* __restrict__ uug) {
  __shared__ float rar[NPG_];
  const int g = blockIdx.x / 5, q = blockIdx.x % 5;   // grid 320
  const int nb = g * NPG_;
  const int t = threadIdx.x;
  for (int i = t; i < NPG_; i += 320) rar[i] = rarr[nb + i];
  __syncthreads();
  const int vl = q * 320 + t;
  const int v = nb + vl;
  const int rs = offs[v], re = rend[v];
  float sum = 0.f;
  int k = rs;
  for (; k + 4 <= re; k += 4) {
    sum += rar[csr[k]] + rar[csr[k + 1]];
    sum += rar[csr[k + 2]] + rar[csr[k + 3]];
  }
  for (; k < re; ++k) sum += rar[csr[k]];
  const float s = tanhf(sum + brel[0] + tarr[v]);
  scoreg[v] = s;
  const unsigned ub = __float_as_uint(s);
  uug[v] = (ub & 0x80000000u) ? ~ub : (ub | 0x80000000u);
}

// ---------------------------------------------------------------------------
// K4b: per-graph radix-select top-K (stable, index tie-break) on staged keys.
// Also zeroes the out slice.
// ---------------------------------------------------------------------------
__global__ __launch_bounds__(1024) void k_topk(
    const unsigned* __restrict__ uug, int* __restrict__ kept,
    float* __restrict__ out) {
  __shared__ unsigned uu[NPG_];
  __shared__ int kp[NPG_];
  __shared__ int hist[256];
  __shared__ int part[16];
  __shared__ int scal[2];
  const int g = blockIdx.x, t = threadIdx.x;
  const int lane = t & 63, wid = t >> 6;
  const int nb = g * NPG_;

  for (int i = t; i < NPG_; i += 1024) uu[i] = uug[nb + i];
  if (t == 0) { scal[0] = 0; scal[1] = KEEP_; }
  __syncthreads();

  const unsigned maskTab[4] = {0u, 0xFF000000u, 0xFFFF0000u, 0xFFFFFF00u};
  const int shTab[4] = {24, 16, 8, 0};
  for (int pass = 0; pass < 4; ++pass) {
    const unsigned lo = (unsigned)scal[0];
    const int remc = scal[1];
    const unsigned msk = maskTab[pass];
    const int sh = shTab[pass];
    if (t < 256) hist[t] = 0;
    __syncthreads();
    for (int v = t; v < NPG_; v += 1024) {
      const unsigned u = uu[v];
      if (((u ^ lo) & msk) == 0) atomicAdd(&hist[(u >> sh) & 255], 1);
    }
    __syncthreads();
    int hv = 0;
    if (t < 256) hv = hist[t];
    int incl = hv;
#pragma unroll
    for (int m = 1; m < 64; m <<= 1) {
      const int u2 = __shfl_up(incl, m);
      if (lane >= m) incl += u2;
    }
    if (t < 256 && lane == 63) part[wid] = incl;
    __syncthreads();
    if (t < 256) {
      int woff = 0;
      for (int w2 = 0; w2 < wid; ++w2) woff += part[w2];
      const int tot = part[0] + part[1] + part[2] + part[3];
      const int sb = tot - (incl + woff) + hv;    // suffix sum from bin t
      const int sb1 = sb - hv;
      if (sb >= remc && sb1 < remc) {             // unique boundary bin
        scal[0] = (int)(lo | ((unsigned)t << sh));
        scal[1] = remc - sb1;
      }
    }
    __syncthreads();
  }
  const unsigned T = (unsigned)scal[0];
  const int remT = scal[1];

  const int i0 = 2 * t, i1 = 2 * t + 1;
  int f0 = 0, f1 = 0;
  if (i0 < NPG_) f0 = (uu[i0] == T);
  if (i1 < NPG_) f1 = (uu[i1] == T);
  int incl2 = f0 + f1;
#pragma unroll
  for (int m = 1; m < 64; m <<= 1) {
    const int u2 = __shfl_up(incl2, m);
    if (lane >= m) incl2 += u2;
  }
  if (lane == 63) part[wid] = incl2;
  __syncthreads();
  int woff2 = 0;
  for (int w2 = 0; w2 < wid; ++w2) woff2 += part[w2];
  const int excl = incl2 + woff2 - (f0 + f1);
  if (i0 < NPG_) kp[i0] = (uu[i0] > T) || (f0 && excl < remT);
  if (i1 < NPG_) kp[i1] = (uu[i1] > T) || (f1 && (excl + f0) < remT);
  __syncthreads();
  for (int v = t; v < NPG_; v += 1024) kept[nb + v] = kp[v];
  if (t < HOUT_) out[g * HOUT_ + t] = 0.f;
}

// ---------------------------------------------------------------------------
// K4c: filtered degree + dis2 + wv + h1w at full occupancy.
// ---------------------------------------------------------------------------
__global__ __launch_bounds__(320) void k_post(
    const unsigned short* __restrict__ csr, const int* __restrict__ offs,
    const int* __restrict__ rend, const int* __restrict__ kept,
    const float* __restrict__ scoreg, const float* __restrict__ h1,
    float* __restrict__ dis2, float* __restrict__ h1w) {
  __shared__ int kp[NPG_];
  __shared__ float wvs[320];
  const int g = blockIdx.x / 5, q = blockIdx.x % 5;   // grid 320
  const int nb = g * NPG_;
  const int t = threadIdx.x;
  for (int i = t; i < NPG_; i += 320) kp[i] = kept[nb + i];
  __syncthreads();
  const int vl = q * 320 + t;
  const int v = nb + vl;
  float w = 0.f;
  if (kp[vl]) {
    const int rs = offs[v], re = rend[v];
    int c2 = 0, k = rs;
    for (; k + 4 <= re; k += 4) {
      c2 += kp[csr[k]] + kp[csr[k + 1]];
      c2 += kp[csr[k + 2]] + kp[csr[k + 3]];
    }
    for (; k < re; ++k) c2 += kp[csr[k]];
    const float d2 = rsqrtf((float)c2 + 1.0f);
    dis2[v] = d2;
    w = scoreg[v] * d2;
  }
  wvs[t] = w;
  __syncthreads();
  const size_t base = (size_t)(nb + q * 320) * 16;
  for (int i = t; i < 320 * 16; i += 320)
    h1w[base + i] = h1[base + i] * wvs[i >> 4];
}

// ---------------------------------------------------------------------------
// K5: conv2 gather, LDS-staged.
// ---------------------------------------------------------------------------
__global__ __launch_bounds__(1024) void k_conv2l(
    const unsigned short* __restrict__ csr, const int* __restrict__ offs,
    const int* __restrict__ rend, const float* __restrict__ h1w,
    const int* __restrict__ kept, const float* __restrict__ dis2,
    float* __restrict__ y16) {
  __shared__ float hds[NPG_ * 16];                // 102,400 B
  const int g = blockIdx.x >> 2, q = blockIdx.x & 3;
  const int nb = g * NPG_;
  const int t = threadIdx.x;
  {
    const float4* src = reinterpret_cast<const float4*>(h1w + (size_t)nb * 16);
    float4* dst = reinterpret_cast<float4*>(hds);
    for (int i = t; i < NPG_ * 4; i += 1024) dst[i] = src[i];
  }
  __syncthreads();
  const int c = t & 15;
  const int vend = q * 400 + 400;
  for (int vl = q * 400 + (t >> 4); vl < vend; vl += 64) {
    const int v = nb + vl;
    if (!kept[v]) continue;                       // uniform per 16-group
    const int rs = offs[v], re = rend[v];
    float acc = 0.f;
    int k = rs;
    for (; k + 4 <= re; k += 4) {
      const int s0 = csr[k], s1 = csr[k + 1];
      const int s2 = csr[k + 2], s3 = csr[k + 3];
      acc += hds[s0 * 16 + c] + hds[s1 * 16 + c];
      acc += hds[s2 * 16 + c] + hds[s3 * 16 + c];
    }
    for (; k < re; ++k) acc += hds[csr[k] * 16 + c];
    acc += hds[vl * 16 + c];                      // self loop
    y16[(size_t)v * 16 + c] = acc * dis2[v];
  }
}

// ---------------------------------------------------------------------------
// K6: out[g] += relu(y16[v]@W2 + b2)/K  fused GEMM+ReLU+mean-pool.
// (r13 scalar version restored -- the r14 MFMA rewrite was ~6x slower:
// per-wave B re-reads from LDS + serial d-chain + 1 block/CU occupancy.)
// ---------------------------------------------------------------------------
__global__ __launch_bounds__(256, 1) void k_gemm2pool(const float* __restrict__ y16,
                                                      const int* __restrict__ kept,
                                                      const float* __restrict__ W2,
                                                      const float* __restrict__ b2,
                                                      float* __restrict__ out) {
  __shared__ float red[256];
  const int blk = blockIdx.x;                     // grid 2048
  const int g = blk >> 5;
  const int sub = blk & 31;
  const int jbase = (sub & 1) * 256;
  const int nstart = g * NPG_ + (sub >> 1) * 100;
  const int tid = threadIdx.x;
  const int wave = tid >> 6, lane = tid & 63;

  float w[16][4];
#pragma unroll
  for (int k = 0; k < 16; ++k)
#pragma unroll
    for (int c = 0; c < 4; ++c)
      w[k][c] = W2[k * HOUT_ + jbase + lane + c * 64];
  float b2r[4];
#pragma unroll
  for (int c = 0; c < 4; ++c) b2r[c] = b2[jbase + lane + c * 64];

  float acc[4] = {0.f, 0.f, 0.f, 0.f};
  for (int i = wave; i < 100; i += 4) {
    const int v = nstart + i;
    if (!kept[v]) continue;                       // wave-uniform
    const float4* yp = reinterpret_cast<const float4*>(y16 + (size_t)v * 16);
    float4 q0 = yp[0], q1 = yp[1], q2 = yp[2], q3 = yp[3];
    const float yv[16] = {q0.x, q0.y, q0.z, q0.w, q1.x, q1.y, q1.z, q1.w,
                          q2.x, q2.y, q2.z, q2.w, q3.x, q3.y, q3.z, q3.w};
    float z[4] = {b2r[0], b2r[1], b2r[2], b2r[3]};
#pragma unroll
    for (int k = 0; k < 16; ++k)
#pragma unroll
      for (int c = 0; c < 4; ++c)
        z[c] = fmaf(yv[k], w[k][c], z[c]);
#pragma unroll
    for (int c = 0; c < 4; ++c) acc[c] += fmaxf(z[c], 0.f);
  }

  red[tid] = 0.f;
  __syncthreads();
#pragma unroll
  for (int c = 0; c < 4; ++c) atomicAdd(&red[lane + 64 * c], acc[c]);
  __syncthreads();
  atomicAdd(&out[g * HOUT_ + jbase + tid], red[tid] * (1.0f / (float)KEEP_));
}

// ---------------------------------------------------------------------------
extern "C" void kernel_launch(void* const* d_in, const int* in_sizes, int n_in,
                              void* d_out, int out_size, void* d_ws, size_t ws_size,
                              hipStream_t stream) {
  (void)in_sizes; (void)n_in; (void)out_size; (void)ws_size;
  const float* x     = (const float*)d_in[0];
  const int*   ei    = (const int*)  d_in[1];
  const float* W1    = (const float*)d_in[3];
  const float* b1    = (const float*)d_in[4];
  const float* Wrel  = (const float*)d_in[5];
  const float* brel  = (const float*)d_in[6];
  const float* Wroot = (const float*)d_in[7];
  const float* W2    = (const float*)d_in[8];
  const float* b2    = (const float*)d_in[9];
  const int* esrc = ei;
  const int* edst = ei + E_;

  // slab quarters: hd / h1 / h1w / y16.  hd (q0) is dead after k_conv1l ->
  // reused for radix keys (uug) and scores (scoreg).
  char* ws = (char*)d_ws;
  float*          hd     = (float*)(ws);                    // q0: 6,553,600 B
  unsigned*       uug    = (unsigned*)(ws);                 //   reuse of q0
  float*          scoreg = (float*)(ws + 409600);           //   reuse of q0
  float*          h1     = (float*)(ws + 6553600);          // q1
  float*          h1w    = (float*)(ws + 13107200);         // q2
  float*          y16    = (float*)(ws + 19660800);         // q3
  unsigned short* csr    = (unsigned short*)(ws + 26214400);// 6,553,600 B
  int*            offs   = (int*)(ws + 32768000);
  int*            rendp  = (int*)(ws + 33177600);
  float*          dis    = (float*)(ws + 33587200);
  int*            kept   = (int*)(ws + 33996800);
  float*          rarr   = (float*)(ws + 34406400);
  float*          tarr   = (float*)(ws + 34816000);
  float*          dis2   = (float*)(ws + 35225600);
  float*          out    = (float*)d_out;

  hipLaunchKernelGGL(k_bx,        dim3(464),   dim3(1024), 0, stream,
                     esrc, edst, offs, rendp, dis, csr, x, W1, hd);
  hipLaunchKernelGGL(k_conv1l,    dim3(256),   dim3(1024), 0, stream,
                     csr, offs, rendp, hd, dis, b1, Wrel, Wroot, h1, rarr, tarr);
  hipLaunchKernelGGL(k_score,     dim3(320),   dim3(320),  0, stream,
                     csr, offs, rendp, rarr, tarr, brel, scoreg, uug);
  hipLaunchKernelGGL(k_topk,      dim3(G_),    dim3(1024), 0, stream,
                     uug, kept, out);
  hipLaunchKernelGGL(k_post,      dim3(320),   dim3(320),  0, stream,
                     csr, offs, rendp, kept, scoreg, h1, dis2, h1w);
  hipLaunchKernelGGL(k_conv2l,    dim3(256),   dim3(1024), 0, stream,
                     csr, offs, rendp, h1w, kept, dis2, y16);
  hipLaunchKernelGGL(k_gemm2pool, dim3(2048),  dim3(256),  0, stream,
                     y16, kept, W2, b2, out);
}